// Round 11
// baseline (7585.752 us; speedup 1.0000x reference)
//
#include <hip/hip_runtime.h>

// RecurrentGaussianActor: fused LSTM(64->256) + Linear+ReLU(256) + 2 heads(16).
// One WG per batch row (256 WGs x 512 threads), persistent over T=1000 steps.
//
// Round-11: r8 (best, 4300us) with the register OVERFLOW removed at the
// source. Budget model (reconciled vs occupancy across r0-r10): wave budget
// = 256 unified regs at launch_bounds(512,2). r0/r4 fit (192 wreg + ~40
// temps); r8/r10's pipeline -> ~280 demand -> allocator spills ~3 loop-
// invariant h8 to scratch, reloaded EVERY step at HBM latency (FETCH 6.2 GB
// = 3 x 16B x 512 x 8 x 125 x 256, exactly). Trimming temps (r10) didn't
// move it. Fix: shrink PERSISTENT state instead:
//  * wreg 48 -> 40 h8 (slices 4..13 per gate): frees 32 regs = the overflow.
//  * tail slices 14,15 per gate (8 h8) are STREAMED per step from global/L2
//    via volatile loads issued right after the LDS-weight phase (u/v dbuf
//    regs die there -> peak-live flat), consumed ~600 issue-cyc later in the
//    final 2 clusters (L2 ~250 cyc covered). whh is L2-resident (512 KB/XCD).
//  * accumulation order identical to r8 (slices ascending) -> same numerics.
//  * everything else r8-verbatim: LDS-w dbuf pipeline, hv rotation, layer2
//    W2 dbuf, heads, xg [t][u][4g], padded dbuf hbuf, 1 barrier/step.
// THE tell: FETCH < 1.5 GB = fit (stream hits L2, not HBM); FETCH >= 5 GB =
// allocator still over -> r8 stands as configuration of record.

#define NB 256
#define NT 1000
#define NF 64
#define NH 256
#define NG 1024
#define NA 16
#define NTHREADS 512
#define CHUNK 8
#define NCHUNK (NT / CHUNK)
#define HHALF 68  // h2 units per padded h-half: 128 f16 = 64 h2, +4 h2 pad = 272 B

typedef _Float16 h2 __attribute__((ext_vector_type(2)));
typedef _Float16 h4 __attribute__((ext_vector_type(4)));
typedef _Float16 h8 __attribute__((ext_vector_type(8)));
typedef float f4 __attribute__((ext_vector_type(4)));

__device__ __forceinline__ float fdot2(h2 a, h2 b, float c) {
  return __builtin_amdgcn_fdot2(a, b, c, false);
}
__device__ __forceinline__ float fexp2(float x) { return __builtin_amdgcn_exp2f(x); }
__device__ __forceinline__ float frcp(float x) { return __builtin_amdgcn_rcpf(x); }
__device__ __forceinline__ float sigmoidf_(float x) {
  return frcp(1.f + fexp2(-1.4426950408889634f * x));
}
__device__ __forceinline__ float tanhfast(float x) {
  float a = fabsf(x);
  float e = fexp2(-2.8853900817779268f * a);
  float r = (1.f - e) * frcp(1.f + e);
  return __builtin_copysignf(r, x);
}
// dot of 8 f16 elements held in two h8 vectors (4 chained v_dot2_f32_f16)
__device__ __forceinline__ float dot8(h8 x, h8 w, float acc) {
  acc = fdot2(__builtin_shufflevector(x, x, 0, 1), __builtin_shufflevector(w, w, 0, 1), acc);
  acc = fdot2(__builtin_shufflevector(x, x, 2, 3), __builtin_shufflevector(w, w, 2, 3), acc);
  acc = fdot2(__builtin_shufflevector(x, x, 4, 5), __builtin_shufflevector(w, w, 4, 5), acc);
  acc = fdot2(__builtin_shufflevector(x, x, 6, 7), __builtin_shufflevector(w, w, 6, 7), acc);
  return acc;
}
// quad_perm DPP: CTRL=0xB1 -> lanes (1,0,3,2) [xor1 within each quad]
template <int CTRL>
__device__ __forceinline__ float qperm(float x) {
  return __int_as_float(
      __builtin_amdgcn_update_dpp(0, __float_as_int(x), CTRL, 0xF, 0xF, true));
}

// ---- prep: convert/pack weights to f16 pairs in workspace (round-0 verbatim) ----
__global__ void prep_kernel(const float* __restrict__ Wih, const float* __restrict__ Whh,
                            const float* __restrict__ bih, const float* __restrict__ bhh,
                            const float* __restrict__ W2, const float* __restrict__ Wm,
                            const float* __restrict__ Ws,
                            h2* __restrict__ whh, h2* __restrict__ wih,
                            h2* __restrict__ w2w, h2* __restrict__ wmh,
                            float* __restrict__ bg) {
  int i = blockIdx.x * 256 + threadIdx.x;
  if (i < 1024 * 128) {  // W_hh [1024][256] -> [1024][128] pairs
    int j = i >> 7, p = i & 127;
    whh[i] = h2{(_Float16)Whh[j * 256 + 2 * p], (_Float16)Whh[j * 256 + 2 * p + 1]};
  }
  if (i < 1024 * 32) {   // W_ih [1024][64] -> [1024][32] pairs
    int j = i >> 5, p = i & 31;
    wih[i] = h2{(_Float16)Wih[j * 64 + 2 * p], (_Float16)Wih[j * 64 + 2 * p + 1]};
  }
  if (i < 256 * 128) {   // W2 [256][256] -> [256][128] pairs
    int j = i >> 7, p = i & 127;
    w2w[i] = h2{(_Float16)W2[j * 256 + 2 * p], (_Float16)W2[j * 256 + 2 * p + 1]};
  }
  if (i < 32 * 128) {    // Wm rows 0..15, Ws rows 16..31
    int j = i >> 7, p = i & 127;
    float v0, v1;
    if (j < 16) { v0 = Wm[j * 256 + 2 * p]; v1 = Wm[j * 256 + 2 * p + 1]; }
    else        { v0 = Ws[(j - 16) * 256 + 2 * p]; v1 = Ws[(j - 16) * 256 + 2 * p + 1]; }
    wmh[i] = h2{(_Float16)v0, (_Float16)v1};
  }
  if (i < 1024) bg[i] = bih[i] + bhh[i];
}

// 4-gate dot cluster against wreg column j (reg-weight phase, stride 10)
#define DOT4R(hv, j)                  \
  p0 = dot8(hv, wreg[j], p0);         \
  p1 = dot8(hv, wreg[10 + (j)], p1);  \
  p2 = dot8(hv, wreg[20 + (j)], p2);  \
  p3 = dot8(hv, wreg[30 + (j)], p3);

// ---- main fused persistent kernel: 1 WG per batch row ----
__global__ __launch_bounds__(NTHREADS, 2) void actor_kernel(
    const float* __restrict__ obs,
    const h2* __restrict__ whh, const h2* __restrict__ wih,
    const h2* __restrict__ w2w, const h2* __restrict__ wmh,
    const float* __restrict__ bg, const float* __restrict__ b2,
    const float* __restrict__ bm, const float* __restrict__ bs,
    float* __restrict__ out) {
  // W_hh h8-slices 0..3 of this thread's (4 rows x own h-half): 16 columns
  // of [512] h8; reads lane-linear b128 -> conflict-free (r4/r8 layout).
  __shared__ __align__(16) h8 whh_l[16 * NTHREADS];        // 131072 B
  __shared__ __align__(16) _Float16 xg_l[CHUNK * NG];      // 16384 B [t][u][4g]
  __shared__ __align__(16) h2 hbuf[2][2 * HHALF];          // 1088 B padded dbuf h
  __shared__ __align__(16) h2 hch[CHUNK * NH / 2];         // 4096 B  h history
  __shared__ __align__(16) h2 xbuf[CHUNK * NF / 2];        // 1024 B  obs chunk
  __shared__ __align__(16) h2 x2b[CHUNK * NH / 2];         // 4096 B  layer2 out
  // total 157760 B <= 163840

  const int tid = threadIdx.x;
  const int b = blockIdx.x;
  const int q = tid >> 1;      // hidden unit owned by this lane pair
  const int jhalf = tid & 1;   // h-half [128*jhalf, 128*jhalf+128)

  // ---- register-resident W_hh: h8 slices 4..13 of own half, 4 gate rows ----
  // 40 x h8 = 160 regs persistent (was 192: the 32 freed regs are exactly the
  // measured overflow). VOLATILE: no remat inside the step loop.
  h8 wreg[40];
  {
    const volatile h8* vw = (const volatile h8*)whh;  // row stride = 32 h8
#pragma unroll
    for (int g = 0; g < 4; g++)
#pragma unroll
      for (int jj = 0; jj < 10; jj++)
        wreg[g * 10 + jj] = vw[(g * 256 + q) * 32 + jhalf * 16 + 4 + jj];
  }
  // ---- LDS-resident W_hh: h8s 0..3 of own half, column (g*4+s), idx tid ----
  {
    const h8* whh8 = (const h8*)whh;
#pragma unroll
    for (int g = 0; g < 4; g++)
#pragma unroll
      for (int s = 0; s < 4; s++)
        whh_l[(g * 4 + s) * NTHREADS + tid] = whh8[(g * 256 + q) * 32 + jhalf * 16 + s];
  }
  // ---- per-step STREAMED tail: slices 14,15 per gate, from global (L2) ----
  // 4 loop-invariant volatile base pointers (8 VGPRs); reads re-issued each
  // step (volatile -> no hoist back into persistent regs).
  const volatile h8* vs0 = (const volatile h8*)whh + (0 * 256 + q) * 32 + jhalf * 16 + 14;
  const volatile h8* vs1 = (const volatile h8*)whh + (1 * 256 + q) * 32 + jhalf * 16 + 14;
  const volatile h8* vs2 = (const volatile h8*)whh + (2 * 256 + q) * 32 + jhalf * 16 + 14;
  const volatile h8* vs3 = (const volatile h8*)whh + (3 * 256 + q) * 32 + jhalf * 16 + 14;

  if (tid < 2 * HHALF) hbuf[0][tid] = h2{(_Float16)0.f, (_Float16)0.f};
  float c_state = 0.f;  // replicated across the lane pair
  const float bg0 = bg[tid], bg1 = bg[tid + 512];  // xg bias rows tid, tid+512
  const float b2v = b2[tid & 255];
  const int oh = tid & 31;
  const float hbv = (oh < NA) ? bm[oh] : bs[oh - NA];
  __syncthreads();

  const float* obs_b = obs + (size_t)b * NT * NF;
  float* out_means = out;
  float* out_stds = out + (size_t)NB * NT * NA;
  // weight base pointers: all step-loop LDS w-reads are ds_read with
  // compile-time offset: immediates.
  const h8* wlA = whh_l + tid;                 // gates 0,1: elem (g*4+s)*512
  const h8* wlB = whh_l + 8 * NTHREADS + tid;  // gates 2,3

  for (int ch = 0; ch < NCHUNK; ++ch) {
    const int t0 = ch * CHUNK;

    // ---- stage obs chunk -> f16 pairs in LDS (round-0 verbatim) ----
    if (tid < 128) {
      int t = tid >> 4, fq = tid & 15;
      f4 v = *(const f4*)(obs_b + (size_t)(t0 + t) * NF + fq * 4);
      xbuf[t * 32 + fq * 2] = h2{(_Float16)v[0], (_Float16)v[1]};
      xbuf[t * 32 + fq * 2 + 1] = h2{(_Float16)v[2], (_Float16)v[3]};
    }
    __syncthreads();

    // ---- xg for rows tid and tid+512 (round-0 math, [t][u][4g] store) ----
#pragma unroll
    for (int rr = 0; rr < 2; ++rr) {
      const int row = tid + rr * 512;
      const float bias = rr ? bg1 : bg0;
      float acc[CHUNK];
#pragma unroll
      for (int t = 0; t < CHUNK; t++) acc[t] = bias;
      const h8* wrow = (const h8*)wih + row * 8;
#pragma unroll
      for (int jh = 0; jh < 2; jh++) {
        h8 w[4];
#pragma unroll
        for (int qq = 0; qq < 4; qq++) w[qq] = wrow[jh * 4 + qq];
#pragma unroll
        for (int t = 0; t < CHUNK; t++) {
#pragma unroll
          for (int qq = 0; qq < 4; qq++) {
            h8 xv = *(const h8*)&xbuf[t * 32 + jh * 16 + qq * 4];
            acc[t] = dot8(xv, w[qq], acc[t]);
          }
        }
      }
      const int g = row >> 8, uu = row & 255;
#pragma unroll
      for (int t = 0; t < CHUNK; t++)
        xg_l[(t * 256 + uu) * 4 + g] = (_Float16)acc[t];
    }
    __syncthreads();

    // ---- 8 recurrent LSTM steps, ONE barrier each; r8 pipeline + stream ----
    for (int t = 0; t < CHUNK; t++) {
      const h8* hb8 =
          (const h8*)((const _Float16*)&hbuf[t & 1][jhalf * HHALF]);
      h4 xg4 = *(const h4*)&xg_l[(t * 256 + q) * 4];
      float p0 = 0.f, p1 = 0.f, p2 = 0.f, p3 = 0.f;
      // hv group A + LDS-weight dbuf pipeline (r8-verbatim)
      h8 a0 = hb8[0], a1 = hb8[1], a2 = hb8[2], a3 = hb8[3];
      h8 u0 = wlA[0 * NTHREADS], u1 = wlA[4 * NTHREADS];
      h8 u2 = wlB[0 * NTHREADS], u3 = wlB[4 * NTHREADS];
      h8 v0 = wlA[1 * NTHREADS], v1 = wlA[5 * NTHREADS];
      h8 v2 = wlB[1 * NTHREADS], v3 = wlB[5 * NTHREADS];
      p0 = dot8(a0, u0, p0); p1 = dot8(a0, u1, p1);
      p2 = dot8(a0, u2, p2); p3 = dot8(a0, u3, p3);
      u0 = wlA[2 * NTHREADS]; u1 = wlA[6 * NTHREADS];
      u2 = wlB[2 * NTHREADS]; u3 = wlB[6 * NTHREADS];
      p0 = dot8(a1, v0, p0); p1 = dot8(a1, v1, p1);
      p2 = dot8(a1, v2, p2); p3 = dot8(a1, v3, p3);
      v0 = wlA[3 * NTHREADS]; v1 = wlA[7 * NTHREADS];
      v2 = wlB[3 * NTHREADS]; v3 = wlB[7 * NTHREADS];
      p0 = dot8(a2, u0, p0); p1 = dot8(a2, u1, p1);
      p2 = dot8(a2, u2, p2); p3 = dot8(a2, u3, p3);
      h8 b0 = hb8[4], b1 = hb8[5], b2 = hb8[6], b3 = hb8[7];
      p0 = dot8(a3, v0, p0); p1 = dot8(a3, v1, p1);
      p2 = dot8(a3, v2, p2); p3 = dot8(a3, v3, p3);
      // ---- issue the 8 streamed tail loads NOW (u/v dbuf regs just died;
      // consumed ~600 issue-cycles below -> L2 latency covered) ----
      h8 s0 = vs0[0], s1 = vs0[1];
      h8 s2 = vs1[0], s3 = vs1[1];
      h8 s4 = vs2[0], s5 = vs2[1];
      h8 s6 = vs3[0], s7 = vs3[1];
      // ---- reg-weight phase: 10 clusters (hv j=4..13), refill dist 4 ----
      DOT4R(b0, 0)  a0 = hb8[8];
      DOT4R(b1, 1)  a1 = hb8[9];
      DOT4R(b2, 2)  a2 = hb8[10];
      DOT4R(b3, 3)  a3 = hb8[11];
      DOT4R(a0, 4)  b0 = hb8[12];
      DOT4R(a1, 5)  b1 = hb8[13];
      DOT4R(a2, 6)  b2 = hb8[14];
      DOT4R(a3, 7)  b3 = hb8[15];
      DOT4R(b0, 8)
      DOT4R(b1, 9)
      // ---- streamed tail clusters: slices 14 (hv=b2) and 15 (hv=b3) ----
      p0 = dot8(b2, s0, p0); p1 = dot8(b2, s2, p1);
      p2 = dot8(b2, s4, p2); p3 = dot8(b2, s6, p3);
      p0 = dot8(b3, s1, p0); p1 = dot8(b3, s3, p1);
      p2 = dot8(b3, s5, p2); p3 = dot8(b3, s7, p3);
      // xor-1 DPP butterfly: both lanes of the pair get all 4 full sums.
      p0 += qperm<0xB1>(p0);
      p1 += qperm<0xB1>(p1);
      p2 += qperm<0xB1>(p2);
      p3 += qperm<0xB1>(p3);
      float gi = sigmoidf_(p0 + (float)xg4[0]);
      float gf = sigmoidf_(p1 + (float)xg4[1]);
      float gg = tanhfast(p2 + (float)xg4[2]);
      float go = sigmoidf_(p3 + (float)xg4[3]);
      c_state = gf * c_state + gi * gg;
      float hval = go * tanhfast(c_state);
      if (jhalf == 0) {  // one lane per unit publishes
        _Float16 hh = (_Float16)hval;
        ((_Float16*)&hbuf[(t + 1) & 1][(q >> 7) * HHALF])[q & 127] = hh;
        ((_Float16*)hch)[t * NH + q] = hh;  // history for layer2
      }
      __syncthreads();  // h(t+1) visible; hbuf[t&1] free for step t+2's write
    }

    // ---- layer2: x2 = relu(h @ W2^T + b2); W2 row double-buffered (r8) ----
    {
      const int o = tid & 255;
      const int tb = (tid >> 8) * 4;  // 4 timesteps per thread
      float acc[4] = {b2v, b2v, b2v, b2v};
      const h8* wrow = (const h8*)w2w + o * 32;
      const h8* hs = (const h8*)hch + tb * 32;  // xv = hs[tt*32 + c*4 + qq]
      h8 wa[4], wb[4];
#pragma unroll
      for (int qq = 0; qq < 4; qq++) wa[qq] = wrow[qq];
#pragma unroll
      for (int cc = 0; cc < 4; cc++) {
        const int ce = 2 * cc, codd = 2 * cc + 1;
        const int cn = (2 * cc + 2 < 8) ? 2 * cc + 2 : 7;  // tail reread, harmless
#pragma unroll
        for (int qq = 0; qq < 4; qq++) wb[qq] = wrow[codd * 4 + qq];
#pragma unroll
        for (int tt = 0; tt < 4; tt++)
#pragma unroll
          for (int qq = 0; qq < 4; qq++)
            acc[tt] = dot8(hs[tt * 32 + ce * 4 + qq], wa[qq], acc[tt]);
#pragma unroll
        for (int qq = 0; qq < 4; qq++) wa[qq] = wrow[cn * 4 + qq];
#pragma unroll
        for (int tt = 0; tt < 4; tt++)
#pragma unroll
          for (int qq = 0; qq < 4; qq++)
            acc[tt] = dot8(hs[tt * 32 + codd * 4 + qq], wb[qq], acc[tt]);
      }
#pragma unroll
      for (int tt = 0; tt < 4; tt++)
        ((_Float16*)x2b)[(tb + tt) * NH + o] = (_Float16)fmaxf(acc[tt], 0.f);
    }
    __syncthreads();

    // ---- heads: 32 outputs x 8 timesteps on first 256 threads (verbatim) ----
    if (tid < 256) {
      const int tt = tid >> 5;
      const h8* wrow = (const h8*)wmh + oh * 32;
      float acc = 0.f;
#pragma unroll 4
      for (int c = 0; c < 32; c++) {
        h8 xv = *(const h8*)&x2b[tt * 128 + c * 4];
        acc = dot8(xv, wrow[c], acc);
      }
      acc += hbv;
      const size_t idx = ((size_t)b * NT + (t0 + tt)) * NA + (oh & 15);
      if (oh < NA) {
        out_means[idx] = acc;
      } else {
        float ls = fminf(fmaxf(acc, -20.f), 2.f);
        out_stds[idx] = fexp2(1.4426950408889634f * ls);
      }
    }
    // no trailing barrier: next chunk's first write to x2b (its layer2) is
    // separated from these reads by the staging/xg/step barriers.
  }
}

#undef DOT4R

extern "C" void kernel_launch(void* const* d_in, const int* in_sizes, int n_in,
                              void* d_out, int out_size, void* d_ws, size_t ws_size,
                              hipStream_t stream) {
  const float* obs = (const float*)d_in[0];
  const float* Wih = (const float*)d_in[1];
  const float* Whh = (const float*)d_in[2];
  const float* bih = (const float*)d_in[3];
  const float* bhh = (const float*)d_in[4];
  const float* W2 = (const float*)d_in[5];
  const float* b2 = (const float*)d_in[6];
  const float* Wm = (const float*)d_in[7];
  const float* bm = (const float*)d_in[8];
  const float* Ws = (const float*)d_in[9];
  const float* bs = (const float*)d_in[10];

  char* ws = (char*)d_ws;
  h2* whh = (h2*)(ws + 0);            // 512 KB
  h2* wih = (h2*)(ws + 524288);       // 128 KB
  h2* w2w = (h2*)(ws + 655360);       // 128 KB
  h2* wmh = (h2*)(ws + 786432);       // 16 KB
  float* bg = (float*)(ws + 802816);  // 4 KB

  prep_kernel<<<512, 256, 0, stream>>>(Wih, Whh, bih, bhh, W2, Wm, Ws,
                                       whh, wih, w2w, wmh, bg);
  actor_kernel<<<NB, NTHREADS, 0, stream>>>(obs, whh, wih, w2w, wmh, bg, b2, bm,
                                            bs, (float*)d_out);
}

// Round 12
// 5938.070 us; speedup vs baseline: 1.2775x; 1.2775x over previous
//
#include <hip/hip_runtime.h>

// RecurrentGaussianActor: fused LSTM(64->256) + Linear+ReLU(256) + 2 heads(16).
// One WG per batch row (256 WGs x 512 threads), persistent over T=1000 steps.
//
// Round-12: r8's pipeline + wreg=40 (fits the 256-reg wave budget) + per-step
// tail stream routed through L2 PROPERLY. r11's lesson: volatile global loads
// take the uncached path to HBM (FETCH 6.8GB = the loads themselves, ~900cy
// exposed/step -> 7.6ms). Fix: inline-asm global_load_dwordx4 with DEFAULT
// cache flags (L2-cacheable), asm volatile to pin in-loop without hoisting:
//  * wreg 40 h8 (slices 4..13/gate) = 160 persistent regs; slices 14,15/gate
//    (8 h8) streamed per step from whh (L2-resident: 512KB shared by all 32
//    blocks/XCD).
//  * two batches of 4 loads: batch1 (gates 0,1) issued where the LDS-weight
//    dbuf regs die; batch2 (gates 2,3) 5 clusters later. Peak live ~237.
//  * consumption behind counted waits: s_waitcnt vmcnt(4) for batch1 (~400
//    issue-cy cover), vmcnt(0) for batch2. The waitcnt asm carries the loaded
//    values as "+v" operands so no consumer can be scheduled above the wait.
//  * per-accumulator accumulation order identical to r8 (slices ascending).
//  * everything else r8-verbatim: LDS-w dbuf pipeline, hv rotation, layer2
//    W2 dbuf, heads, xg [t][u][4g], padded dbuf hbuf, 1 barrier/step.
// THE tell: FETCH < 1.5 GB = spill gone AND stream hits L2 -> expect 3.8-4.15
// ms. FETCH >= 5 GB or dur >= 4300 -> r8 stands as configuration of record.

#define NB 256
#define NT 1000
#define NF 64
#define NH 256
#define NG 1024
#define NA 16
#define NTHREADS 512
#define CHUNK 8
#define NCHUNK (NT / CHUNK)
#define HHALF 68  // h2 units per padded h-half: 128 f16 = 64 h2, +4 h2 pad = 272 B

typedef _Float16 h2 __attribute__((ext_vector_type(2)));
typedef _Float16 h4 __attribute__((ext_vector_type(4)));
typedef _Float16 h8 __attribute__((ext_vector_type(8)));
typedef float f4 __attribute__((ext_vector_type(4)));

__device__ __forceinline__ float fdot2(h2 a, h2 b, float c) {
  return __builtin_amdgcn_fdot2(a, b, c, false);
}
__device__ __forceinline__ float fexp2(float x) { return __builtin_amdgcn_exp2f(x); }
__device__ __forceinline__ float frcp(float x) { return __builtin_amdgcn_rcpf(x); }
__device__ __forceinline__ float sigmoidf_(float x) {
  return frcp(1.f + fexp2(-1.4426950408889634f * x));
}
__device__ __forceinline__ float tanhfast(float x) {
  float a = fabsf(x);
  float e = fexp2(-2.8853900817779268f * a);
  float r = (1.f - e) * frcp(1.f + e);
  return __builtin_copysignf(r, x);
}
// dot of 8 f16 elements held in two h8 vectors (4 chained v_dot2_f32_f16)
__device__ __forceinline__ float dot8(h8 x, h8 w, float acc) {
  acc = fdot2(__builtin_shufflevector(x, x, 0, 1), __builtin_shufflevector(w, w, 0, 1), acc);
  acc = fdot2(__builtin_shufflevector(x, x, 2, 3), __builtin_shufflevector(w, w, 2, 3), acc);
  acc = fdot2(__builtin_shufflevector(x, x, 4, 5), __builtin_shufflevector(w, w, 4, 5), acc);
  acc = fdot2(__builtin_shufflevector(x, x, 6, 7), __builtin_shufflevector(w, w, 6, 7), acc);
  return acc;
}
// quad_perm DPP: CTRL=0xB1 -> lanes (1,0,3,2) [xor1 within each quad]
template <int CTRL>
__device__ __forceinline__ float qperm(float x) {
  return __int_as_float(
      __builtin_amdgcn_update_dpp(0, __float_as_int(x), CTRL, 0xF, 0xF, true));
}

// ---- prep: convert/pack weights to f16 pairs in workspace (round-0 verbatim) ----
__global__ void prep_kernel(const float* __restrict__ Wih, const float* __restrict__ Whh,
                            const float* __restrict__ bih, const float* __restrict__ bhh,
                            const float* __restrict__ W2, const float* __restrict__ Wm,
                            const float* __restrict__ Ws,
                            h2* __restrict__ whh, h2* __restrict__ wih,
                            h2* __restrict__ w2w, h2* __restrict__ wmh,
                            float* __restrict__ bg) {
  int i = blockIdx.x * 256 + threadIdx.x;
  if (i < 1024 * 128) {  // W_hh [1024][256] -> [1024][128] pairs
    int j = i >> 7, p = i & 127;
    whh[i] = h2{(_Float16)Whh[j * 256 + 2 * p], (_Float16)Whh[j * 256 + 2 * p + 1]};
  }
  if (i < 1024 * 32) {   // W_ih [1024][64] -> [1024][32] pairs
    int j = i >> 5, p = i & 31;
    wih[i] = h2{(_Float16)Wih[j * 64 + 2 * p], (_Float16)Wih[j * 64 + 2 * p + 1]};
  }
  if (i < 256 * 128) {   // W2 [256][256] -> [256][128] pairs
    int j = i >> 7, p = i & 127;
    w2w[i] = h2{(_Float16)W2[j * 256 + 2 * p], (_Float16)W2[j * 256 + 2 * p + 1]};
  }
  if (i < 32 * 128) {    // Wm rows 0..15, Ws rows 16..31
    int j = i >> 7, p = i & 127;
    float v0, v1;
    if (j < 16) { v0 = Wm[j * 256 + 2 * p]; v1 = Wm[j * 256 + 2 * p + 1]; }
    else        { v0 = Ws[(j - 16) * 256 + 2 * p]; v1 = Ws[(j - 16) * 256 + 2 * p + 1]; }
    wmh[i] = h2{(_Float16)v0, (_Float16)v1};
  }
  if (i < 1024) bg[i] = bih[i] + bhh[i];
}

// 4-gate dot cluster against wreg column j (reg-weight phase, stride 10)
#define DOT4R(hv, j)                  \
  p0 = dot8(hv, wreg[j], p0);         \
  p1 = dot8(hv, wreg[10 + (j)], p1);  \
  p2 = dot8(hv, wreg[20 + (j)], p2);  \
  p3 = dot8(hv, wreg[30 + (j)], p3);

// L2-cached 2x16B stream load (default cache flags; asm volatile pins it
// in-loop without volatile's cache-bypass). "=&v": dest quads must not alias
// the address pair (2nd load reads %2 after %0 is written back).
#define STREAM2(d0, d1, ptr)                              \
  asm volatile("global_load_dwordx4 %0, %2, off\n\t"      \
               "global_load_dwordx4 %1, %2, off offset:16"\
               : "=&v"(d0), "=&v"(d1)                     \
               : "v"(ptr))

// ---- main fused persistent kernel: 1 WG per batch row ----
__global__ __launch_bounds__(NTHREADS, 2) void actor_kernel(
    const float* __restrict__ obs,
    const h2* __restrict__ whh, const h2* __restrict__ wih,
    const h2* __restrict__ w2w, const h2* __restrict__ wmh,
    const float* __restrict__ bg, const float* __restrict__ b2,
    const float* __restrict__ bm, const float* __restrict__ bs,
    float* __restrict__ out) {
  // W_hh h8-slices 0..3 of this thread's (4 rows x own h-half): 16 columns
  // of [512] h8; reads lane-linear b128 -> conflict-free (r4/r8 layout).
  __shared__ __align__(16) h8 whh_l[16 * NTHREADS];        // 131072 B
  __shared__ __align__(16) _Float16 xg_l[CHUNK * NG];      // 16384 B [t][u][4g]
  __shared__ __align__(16) h2 hbuf[2][2 * HHALF];          // 1088 B padded dbuf h
  __shared__ __align__(16) h2 hch[CHUNK * NH / 2];         // 4096 B  h history
  __shared__ __align__(16) h2 xbuf[CHUNK * NF / 2];        // 1024 B  obs chunk
  __shared__ __align__(16) h2 x2b[CHUNK * NH / 2];         // 4096 B  layer2 out
  // total 157760 B <= 163840

  const int tid = threadIdx.x;
  const int b = blockIdx.x;
  const int q = tid >> 1;      // hidden unit owned by this lane pair
  const int jhalf = tid & 1;   // h-half [128*jhalf, 128*jhalf+128)

  // ---- register-resident W_hh: h8 slices 4..13 of own half, 4 gate rows ----
  // 40 x h8 = 160 persistent regs. VOLATILE load-once (no remat in loop).
  h8 wreg[40];
  {
    const volatile h8* vw = (const volatile h8*)whh;  // row stride = 32 h8
#pragma unroll
    for (int g = 0; g < 4; g++)
#pragma unroll
      for (int jj = 0; jj < 10; jj++)
        wreg[g * 10 + jj] = vw[(g * 256 + q) * 32 + jhalf * 16 + 4 + jj];
  }
  // ---- LDS-resident W_hh: h8s 0..3 of own half, column (g*4+s), idx tid ----
  {
    const h8* whh8 = (const h8*)whh;
#pragma unroll
    for (int g = 0; g < 4; g++)
#pragma unroll
      for (int s = 0; s < 4; s++)
        whh_l[(g * 4 + s) * NTHREADS + tid] = whh8[(g * 256 + q) * 32 + jhalf * 16 + s];
  }
  // ---- per-step streamed tail: slices 14,15 per gate, via L2 (asm loads) ----
  const h8* vs0 = (const h8*)whh + (0 * 256 + q) * 32 + jhalf * 16 + 14;
  const h8* vs1 = (const h8*)whh + (1 * 256 + q) * 32 + jhalf * 16 + 14;
  const h8* vs2 = (const h8*)whh + (2 * 256 + q) * 32 + jhalf * 16 + 14;
  const h8* vs3 = (const h8*)whh + (3 * 256 + q) * 32 + jhalf * 16 + 14;

  if (tid < 2 * HHALF) hbuf[0][tid] = h2{(_Float16)0.f, (_Float16)0.f};
  float c_state = 0.f;  // replicated across the lane pair
  const float bg0 = bg[tid], bg1 = bg[tid + 512];  // xg bias rows tid, tid+512
  const float b2v = b2[tid & 255];
  const int oh = tid & 31;
  const float hbv = (oh < NA) ? bm[oh] : bs[oh - NA];
  __syncthreads();

  const float* obs_b = obs + (size_t)b * NT * NF;
  float* out_means = out;
  float* out_stds = out + (size_t)NB * NT * NA;
  // weight base pointers: all step-loop LDS w-reads are ds_read with
  // compile-time offset: immediates.
  const h8* wlA = whh_l + tid;                 // gates 0,1: elem (g*4+s)*512
  const h8* wlB = whh_l + 8 * NTHREADS + tid;  // gates 2,3

  for (int ch = 0; ch < NCHUNK; ++ch) {
    const int t0 = ch * CHUNK;

    // ---- stage obs chunk -> f16 pairs in LDS (round-0 verbatim) ----
    if (tid < 128) {
      int t = tid >> 4, fq = tid & 15;
      f4 v = *(const f4*)(obs_b + (size_t)(t0 + t) * NF + fq * 4);
      xbuf[t * 32 + fq * 2] = h2{(_Float16)v[0], (_Float16)v[1]};
      xbuf[t * 32 + fq * 2 + 1] = h2{(_Float16)v[2], (_Float16)v[3]};
    }
    __syncthreads();

    // ---- xg for rows tid and tid+512 (round-0 math, [t][u][4g] store) ----
#pragma unroll
    for (int rr = 0; rr < 2; ++rr) {
      const int row = tid + rr * 512;
      const float bias = rr ? bg1 : bg0;
      float acc[CHUNK];
#pragma unroll
      for (int t = 0; t < CHUNK; t++) acc[t] = bias;
      const h8* wrow = (const h8*)wih + row * 8;
#pragma unroll
      for (int jh = 0; jh < 2; jh++) {
        h8 w[4];
#pragma unroll
        for (int qq = 0; qq < 4; qq++) w[qq] = wrow[jh * 4 + qq];
#pragma unroll
        for (int t = 0; t < CHUNK; t++) {
#pragma unroll
          for (int qq = 0; qq < 4; qq++) {
            h8 xv = *(const h8*)&xbuf[t * 32 + jh * 16 + qq * 4];
            acc[t] = dot8(xv, w[qq], acc[t]);
          }
        }
      }
      const int g = row >> 8, uu = row & 255;
#pragma unroll
      for (int t = 0; t < CHUNK; t++)
        xg_l[(t * 256 + uu) * 4 + g] = (_Float16)acc[t];
    }
    __syncthreads();

    // ---- 8 recurrent LSTM steps, ONE barrier each; r8 pipeline + L2 tail ----
    for (int t = 0; t < CHUNK; t++) {
      const h8* hb8 =
          (const h8*)((const _Float16*)&hbuf[t & 1][jhalf * HHALF]);
      h4 xg4 = *(const h4*)&xg_l[(t * 256 + q) * 4];
      float p0 = 0.f, p1 = 0.f, p2 = 0.f, p3 = 0.f;
      // hv group A + LDS-weight dbuf pipeline (r8-verbatim, slices 0..3)
      h8 a0 = hb8[0], a1 = hb8[1], a2 = hb8[2], a3 = hb8[3];
      h8 u0 = wlA[0 * NTHREADS], u1 = wlA[4 * NTHREADS];
      h8 u2 = wlB[0 * NTHREADS], u3 = wlB[4 * NTHREADS];
      h8 v0 = wlA[1 * NTHREADS], v1 = wlA[5 * NTHREADS];
      h8 v2 = wlB[1 * NTHREADS], v3 = wlB[5 * NTHREADS];
      p0 = dot8(a0, u0, p0); p1 = dot8(a0, u1, p1);
      p2 = dot8(a0, u2, p2); p3 = dot8(a0, u3, p3);
      u0 = wlA[2 * NTHREADS]; u1 = wlA[6 * NTHREADS];
      u2 = wlB[2 * NTHREADS]; u3 = wlB[6 * NTHREADS];
      p0 = dot8(a1, v0, p0); p1 = dot8(a1, v1, p1);
      p2 = dot8(a1, v2, p2); p3 = dot8(a1, v3, p3);
      v0 = wlA[3 * NTHREADS]; v1 = wlA[7 * NTHREADS];
      v2 = wlB[3 * NTHREADS]; v3 = wlB[7 * NTHREADS];
      p0 = dot8(a2, u0, p0); p1 = dot8(a2, u1, p1);
      p2 = dot8(a2, u2, p2); p3 = dot8(a2, u3, p3);
      h8 b0 = hb8[4], b1 = hb8[5], b2 = hb8[6], b3 = hb8[7];
      p0 = dot8(a3, v0, p0); p1 = dot8(a3, v1, p1);
      p2 = dot8(a3, v2, p2); p3 = dot8(a3, v3, p3);
      // ---- batch1: stream tails of gates 0,1 (u/v dbuf regs just died) ----
      h8 s0, s1, s2, s3, s4, s5, s6, s7;
      STREAM2(s0, s1, vs0);
      STREAM2(s2, s3, vs1);
      // ---- reg-weight phase: clusters 0..4 (slices 4..8) ----
      DOT4R(b0, 0)  a0 = hb8[8];
      DOT4R(b1, 1)  a1 = hb8[9];
      DOT4R(b2, 2)  a2 = hb8[10];
      DOT4R(b3, 3)  a3 = hb8[11];
      DOT4R(a0, 4)  b0 = hb8[12];
      // ---- batch2: stream tails of gates 2,3 ----
      STREAM2(s4, s5, vs2);
      STREAM2(s6, s7, vs3);
      // ---- clusters 5..9 (slices 9..13) ----
      DOT4R(a1, 5)  b1 = hb8[13];
      DOT4R(a2, 6)  b2 = hb8[14];
      DOT4R(a3, 7)  b3 = hb8[15];
      DOT4R(b0, 8)
      DOT4R(b1, 9)
      // ---- batch1 tails: vmcnt(4) = batch1's 4 loads complete ----
      asm volatile("s_waitcnt vmcnt(4)"
                   : "+v"(s0), "+v"(s1), "+v"(s2), "+v"(s3));
      p0 = dot8(b2, s0, p0); p0 = dot8(b3, s1, p0);
      p1 = dot8(b2, s2, p1); p1 = dot8(b3, s3, p1);
      // ---- batch2 tails: vmcnt(0) ----
      asm volatile("s_waitcnt vmcnt(0)"
                   : "+v"(s4), "+v"(s5), "+v"(s6), "+v"(s7));
      p2 = dot8(b2, s4, p2); p2 = dot8(b3, s5, p2);
      p3 = dot8(b2, s6, p3); p3 = dot8(b3, s7, p3);
      // xor-1 DPP butterfly: both lanes of the pair get all 4 full sums.
      p0 += qperm<0xB1>(p0);
      p1 += qperm<0xB1>(p1);
      p2 += qperm<0xB1>(p2);
      p3 += qperm<0xB1>(p3);
      float gi = sigmoidf_(p0 + (float)xg4[0]);
      float gf = sigmoidf_(p1 + (float)xg4[1]);
      float gg = tanhfast(p2 + (float)xg4[2]);
      float go = sigmoidf_(p3 + (float)xg4[3]);
      c_state = gf * c_state + gi * gg;
      float hval = go * tanhfast(c_state);
      if (jhalf == 0) {  // one lane per unit publishes
        _Float16 hh = (_Float16)hval;
        ((_Float16*)&hbuf[(t + 1) & 1][(q >> 7) * HHALF])[q & 127] = hh;
        ((_Float16*)hch)[t * NH + q] = hh;  // history for layer2
      }
      __syncthreads();  // h(t+1) visible; hbuf[t&1] free for step t+2's write
    }

    // ---- layer2: x2 = relu(h @ W2^T + b2); W2 row double-buffered (r8) ----
    {
      const int o = tid & 255;
      const int tb = (tid >> 8) * 4;  // 4 timesteps per thread
      float acc[4] = {b2v, b2v, b2v, b2v};
      const h8* wrow = (const h8*)w2w + o * 32;
      const h8* hs = (const h8*)hch + tb * 32;  // xv = hs[tt*32 + c*4 + qq]
      h8 wa[4], wb[4];
#pragma unroll
      for (int qq = 0; qq < 4; qq++) wa[qq] = wrow[qq];
#pragma unroll
      for (int cc = 0; cc < 4; cc++) {
        const int ce = 2 * cc, codd = 2 * cc + 1;
        const int cn = (2 * cc + 2 < 8) ? 2 * cc + 2 : 7;  // tail reread, harmless
#pragma unroll
        for (int qq = 0; qq < 4; qq++) wb[qq] = wrow[codd * 4 + qq];
#pragma unroll
        for (int tt = 0; tt < 4; tt++)
#pragma unroll
          for (int qq = 0; qq < 4; qq++)
            acc[tt] = dot8(hs[tt * 32 + ce * 4 + qq], wa[qq], acc[tt]);
#pragma unroll
        for (int qq = 0; qq < 4; qq++) wa[qq] = wrow[cn * 4 + qq];
#pragma unroll
        for (int tt = 0; tt < 4; tt++)
#pragma unroll
          for (int qq = 0; qq < 4; qq++)
            acc[tt] = dot8(hs[tt * 32 + codd * 4 + qq], wb[qq], acc[tt]);
      }
#pragma unroll
      for (int tt = 0; tt < 4; tt++)
        ((_Float16*)x2b)[(tb + tt) * NH + o] = (_Float16)fmaxf(acc[tt], 0.f);
    }
    __syncthreads();

    // ---- heads: 32 outputs x 8 timesteps on first 256 threads (verbatim) ----
    if (tid < 256) {
      const int tt = tid >> 5;
      const h8* wrow = (const h8*)wmh + oh * 32;
      float acc = 0.f;
#pragma unroll 4
      for (int c = 0; c < 32; c++) {
        h8 xv = *(const h8*)&x2b[tt * 128 + c * 4];
        acc = dot8(xv, wrow[c], acc);
      }
      acc += hbv;
      const size_t idx = ((size_t)b * NT + (t0 + tt)) * NA + (oh & 15);
      if (oh < NA) {
        out_means[idx] = acc;
      } else {
        float ls = fminf(fmaxf(acc, -20.f), 2.f);
        out_stds[idx] = fexp2(1.4426950408889634f * ls);
      }
    }
    // no trailing barrier: next chunk's first write to x2b (its layer2) is
    // separated from these reads by the staging/xg/step barriers.
  }
}

#undef DOT4R
#undef STREAM2

extern "C" void kernel_launch(void* const* d_in, const int* in_sizes, int n_in,
                              void* d_out, int out_size, void* d_ws, size_t ws_size,
                              hipStream_t stream) {
  const float* obs = (const float*)d_in[0];
  const float* Wih = (const float*)d_in[1];
  const float* Whh = (const float*)d_in[2];
  const float* bih = (const float*)d_in[3];
  const float* bhh = (const float*)d_in[4];
  const float* W2 = (const float*)d_in[5];
  const float* b2 = (const float*)d_in[6];
  const float* Wm = (const float*)d_in[7];
  const float* bm = (const float*)d_in[8];
  const float* Ws = (const float*)d_in[9];
  const float* bs = (const float*)d_in[10];

  char* ws = (char*)d_ws;
  h2* whh = (h2*)(ws + 0);            // 512 KB
  h2* wih = (h2*)(ws + 524288);       // 128 KB
  h2* w2w = (h2*)(ws + 655360);       // 128 KB
  h2* wmh = (h2*)(ws + 786432);       // 16 KB
  float* bg = (float*)(ws + 802816);  // 4 KB

  prep_kernel<<<512, 256, 0, stream>>>(Wih, Whh, bih, bhh, W2, Wm, Ws,
                                       whh, wih, w2w, wmh, bg);
  actor_kernel<<<NB, NTHREADS, 0, stream>>>(obs, whh, wih, w2w, wmh, bg, b2, bm,
                                            bs, (float*)d_out);
}

// Round 13
// 4307.457 us; speedup vs baseline: 1.7611x; 1.3786x over previous
//
#include <hip/hip_runtime.h>

// RecurrentGaussianActor: fused LSTM(64->256) + Linear+ReLU(256) + 2 heads(16).
// One WG per batch row (256 WGs x 512 threads), persistent over T=1000 steps.
//
// CONFIGURATION OF RECORD (measured 4300us, round 8). Structure: r4 base
// (512 thr, launch_bounds(512,2), 48xh8 volatile weight regs in AGPR, 16-col
// LDS W_hh, DPP xor-1 gate exchange, 1 barrier/step) + explicit software
// pipeline in the step loop and layer2 (every ds_read issued >=1 dot-group
// before first use; weight bases wlA/wlB give compile-time offset: reads).
//
// Known property: the pipeline temps push register demand ~26 over the
// 256-reg wave budget -> the allocator spills ~3 loop-invariant h8, reloaded
// per step from scratch (FETCH ~6.4 GB). Rounds 10-12 proved this reload is
// NOT on the critical path: temps-trim (r10, 4336us), volatile stream (r11,
// 7586us, uncached HBM path), and asm L2 stream (r12, 5938us, waits fenced
// the scheduler) were all neutral-to-worse. Closed searches: thread shape
// (1024/256 thr spill or starve TLP: r1-r3, r9), weight placement (192 AGPR
// + 128 arch is the allocator fixed point: r7/r9), barrier count (r4),
// rows/WG (r5), JIT-fused xg (r6). Remaining bound is per-step latency
// (barrier + LDS chains at 8 waves/CU, weight-residency-capped) -- a
// structural minimum for this decomposition, not a BW/compute roofline.

#define NB 256
#define NT 1000
#define NF 64
#define NH 256
#define NG 1024
#define NA 16
#define NTHREADS 512
#define CHUNK 8
#define NCHUNK (NT / CHUNK)
#define HHALF 68  // h2 units per padded h-half: 128 f16 = 64 h2, +4 h2 pad = 272 B

typedef _Float16 h2 __attribute__((ext_vector_type(2)));
typedef _Float16 h4 __attribute__((ext_vector_type(4)));
typedef _Float16 h8 __attribute__((ext_vector_type(8)));
typedef float f4 __attribute__((ext_vector_type(4)));

__device__ __forceinline__ float fdot2(h2 a, h2 b, float c) {
  return __builtin_amdgcn_fdot2(a, b, c, false);
}
__device__ __forceinline__ float fexp2(float x) { return __builtin_amdgcn_exp2f(x); }
__device__ __forceinline__ float frcp(float x) { return __builtin_amdgcn_rcpf(x); }
__device__ __forceinline__ float sigmoidf_(float x) {
  return frcp(1.f + fexp2(-1.4426950408889634f * x));
}
__device__ __forceinline__ float tanhfast(float x) {
  float a = fabsf(x);
  float e = fexp2(-2.8853900817779268f * a);
  float r = (1.f - e) * frcp(1.f + e);
  return __builtin_copysignf(r, x);
}
// dot of 8 f16 elements held in two h8 vectors (4 chained v_dot2_f32_f16)
__device__ __forceinline__ float dot8(h8 x, h8 w, float acc) {
  acc = fdot2(__builtin_shufflevector(x, x, 0, 1), __builtin_shufflevector(w, w, 0, 1), acc);
  acc = fdot2(__builtin_shufflevector(x, x, 2, 3), __builtin_shufflevector(w, w, 2, 3), acc);
  acc = fdot2(__builtin_shufflevector(x, x, 4, 5), __builtin_shufflevector(w, w, 4, 5), acc);
  acc = fdot2(__builtin_shufflevector(x, x, 6, 7), __builtin_shufflevector(w, w, 6, 7), acc);
  return acc;
}
// quad_perm DPP: CTRL=0xB1 -> lanes (1,0,3,2) [xor1 within each quad]
template <int CTRL>
__device__ __forceinline__ float qperm(float x) {
  return __int_as_float(
      __builtin_amdgcn_update_dpp(0, __float_as_int(x), CTRL, 0xF, 0xF, true));
}

// ---- prep: convert/pack weights to f16 pairs in workspace (round-0 verbatim) ----
__global__ void prep_kernel(const float* __restrict__ Wih, const float* __restrict__ Whh,
                            const float* __restrict__ bih, const float* __restrict__ bhh,
                            const float* __restrict__ W2, const float* __restrict__ Wm,
                            const float* __restrict__ Ws,
                            h2* __restrict__ whh, h2* __restrict__ wih,
                            h2* __restrict__ w2w, h2* __restrict__ wmh,
                            float* __restrict__ bg) {
  int i = blockIdx.x * 256 + threadIdx.x;
  if (i < 1024 * 128) {  // W_hh [1024][256] -> [1024][128] pairs
    int j = i >> 7, p = i & 127;
    whh[i] = h2{(_Float16)Whh[j * 256 + 2 * p], (_Float16)Whh[j * 256 + 2 * p + 1]};
  }
  if (i < 1024 * 32) {   // W_ih [1024][64] -> [1024][32] pairs
    int j = i >> 5, p = i & 31;
    wih[i] = h2{(_Float16)Wih[j * 64 + 2 * p], (_Float16)Wih[j * 64 + 2 * p + 1]};
  }
  if (i < 256 * 128) {   // W2 [256][256] -> [256][128] pairs
    int j = i >> 7, p = i & 127;
    w2w[i] = h2{(_Float16)W2[j * 256 + 2 * p], (_Float16)W2[j * 256 + 2 * p + 1]};
  }
  if (i < 32 * 128) {    // Wm rows 0..15, Ws rows 16..31
    int j = i >> 7, p = i & 127;
    float v0, v1;
    if (j < 16) { v0 = Wm[j * 256 + 2 * p]; v1 = Wm[j * 256 + 2 * p + 1]; }
    else        { v0 = Ws[(j - 16) * 256 + 2 * p]; v1 = Ws[(j - 16) * 256 + 2 * p + 1]; }
    wmh[i] = h2{(_Float16)v0, (_Float16)v1};
  }
  if (i < 1024) bg[i] = bih[i] + bhh[i];
}

// ---- main fused persistent kernel: 1 WG per batch row ----
__global__ __launch_bounds__(NTHREADS, 2) void actor_kernel(
    const float* __restrict__ obs,
    const h2* __restrict__ whh, const h2* __restrict__ wih,
    const h2* __restrict__ w2w, const h2* __restrict__ wmh,
    const float* __restrict__ bg, const float* __restrict__ b2,
    const float* __restrict__ bm, const float* __restrict__ bs,
    float* __restrict__ out) {
  // W_hh h8-slices 0..3 of this thread's (4 rows x own h-half): 16 columns
  // of [512] h8; reads lane-linear b128 -> conflict-free (r4 layout).
  __shared__ __align__(16) h8 whh_l[16 * NTHREADS];        // 131072 B
  __shared__ __align__(16) _Float16 xg_l[CHUNK * NG];      // 16384 B [t][u][4g]
  __shared__ __align__(16) h2 hbuf[2][2 * HHALF];          // 1088 B padded dbuf h
  __shared__ __align__(16) h2 hch[CHUNK * NH / 2];         // 4096 B  h history
  __shared__ __align__(16) h2 xbuf[CHUNK * NF / 2];        // 1024 B  obs chunk
  __shared__ __align__(16) h2 x2b[CHUNK * NH / 2];         // 4096 B  layer2 out
  // total 157760 B <= 163840

  const int tid = threadIdx.x;
  const int b = blockIdx.x;
  const int q = tid >> 1;      // hidden unit owned by this lane pair
  const int jhalf = tid & 1;   // h-half [128*jhalf, 128*jhalf+128)

  // ---- register-resident W_hh: h8s 4..15 of own half, 4 gate rows of q ----
  // 48 x h8 = 192 regs (the allocator's stable AGPR footprint). VOLATILE:
  // no remat-from-global inside the step loop.
  h8 wreg[48];
  {
    const volatile h8* vw = (const volatile h8*)whh;  // row stride = 32 h8
#pragma unroll
    for (int g = 0; g < 4; g++)
#pragma unroll
      for (int jj = 0; jj < 12; jj++)
        wreg[g * 12 + jj] = vw[(g * 256 + q) * 32 + jhalf * 16 + 4 + jj];
  }
  // ---- LDS-resident W_hh: h8s 0..3 of own half, column (g*4+s), idx tid ----
  {
    const h8* whh8 = (const h8*)whh;
#pragma unroll
    for (int g = 0; g < 4; g++)
#pragma unroll
      for (int s = 0; s < 4; s++)
        whh_l[(g * 4 + s) * NTHREADS + tid] = whh8[(g * 256 + q) * 32 + jhalf * 16 + s];
  }
  if (tid < 2 * HHALF) hbuf[0][tid] = h2{(_Float16)0.f, (_Float16)0.f};
  float c_state = 0.f;  // replicated across the lane pair
  const float bg0 = bg[tid], bg1 = bg[tid + 512];  // xg bias rows tid, tid+512
  const float b2v = b2[tid & 255];
  const int oh = tid & 31;
  const float hbv = (oh < NA) ? bm[oh] : bs[oh - NA];
  __syncthreads();

  const float* obs_b = obs + (size_t)b * NT * NF;
  float* out_means = out;
  float* out_stds = out + (size_t)NB * NT * NA;
  // weight base pointers: all 16 step-loop w-reads become ds_read with
  // compile-time offset: immediates (byte offsets <= 57344 < 64K).
  const h8* wlA = whh_l + tid;                 // gates 0,1: elem (g*4+s)*512
  const h8* wlB = whh_l + 8 * NTHREADS + tid;  // gates 2,3

  for (int ch = 0; ch < NCHUNK; ++ch) {
    const int t0 = ch * CHUNK;

    // ---- stage obs chunk -> f16 pairs in LDS (round-0 verbatim) ----
    if (tid < 128) {
      int t = tid >> 4, fq = tid & 15;
      f4 v = *(const f4*)(obs_b + (size_t)(t0 + t) * NF + fq * 4);
      xbuf[t * 32 + fq * 2] = h2{(_Float16)v[0], (_Float16)v[1]};
      xbuf[t * 32 + fq * 2 + 1] = h2{(_Float16)v[2], (_Float16)v[3]};
    }
    __syncthreads();

    // ---- xg for rows tid and tid+512 (round-0 math, [t][u][4g] store) ----
#pragma unroll
    for (int rr = 0; rr < 2; ++rr) {
      const int row = tid + rr * 512;
      const float bias = rr ? bg1 : bg0;
      float acc[CHUNK];
#pragma unroll
      for (int t = 0; t < CHUNK; t++) acc[t] = bias;
      const h8* wrow = (const h8*)wih + row * 8;
#pragma unroll
      for (int jh = 0; jh < 2; jh++) {
        h8 w[4];
#pragma unroll
        for (int qq = 0; qq < 4; qq++) w[qq] = wrow[jh * 4 + qq];
#pragma unroll
        for (int t = 0; t < CHUNK; t++) {
#pragma unroll
          for (int qq = 0; qq < 4; qq++) {
            h8 xv = *(const h8*)&xbuf[t * 32 + jh * 16 + qq * 4];
            acc[t] = dot8(xv, w[qq], acc[t]);
          }
        }
      }
      const int g = row >> 8, uu = row & 255;
#pragma unroll
      for (int t = 0; t < CHUNK; t++)
        xg_l[(t * 256 + uu) * 4 + g] = (_Float16)acc[t];
    }
    __syncthreads();

    // ---- 8 recurrent LSTM steps, ONE barrier each; software-pipelined ----
    // Every ds_read is issued >= one dot-group (~128 issue cyc) before its
    // first consumer: hv rotates through a0-3/b0-3, LDS weights through
    // u0-3/v0-3. Same operands/order-of-accumulation as r4.
    for (int t = 0; t < CHUNK; t++) {
      const h8* hb8 =
          (const h8*)((const _Float16*)&hbuf[t & 1][jhalf * HHALF]);
      // issue: hv group A (j=0..3) + w(s=0)
      h8 a0 = hb8[0], a1 = hb8[1], a2 = hb8[2], a3 = hb8[3];
      h8 u0 = wlA[0 * NTHREADS], u1 = wlA[4 * NTHREADS];
      h8 u2 = wlB[0 * NTHREADS], u3 = wlB[4 * NTHREADS];
      h4 xg4 = *(const h4*)&xg_l[(t * 256 + q) * 4];
      float p0 = 0.f, p1 = 0.f, p2 = 0.f, p3 = 0.f;
      // s=0: issue w(s=1); consume a0 x u*
      h8 v0 = wlA[1 * NTHREADS], v1 = wlA[5 * NTHREADS];
      h8 v2 = wlB[1 * NTHREADS], v3 = wlB[5 * NTHREADS];
      p0 = dot8(a0, u0, p0); p1 = dot8(a0, u1, p1);
      p2 = dot8(a0, u2, p2); p3 = dot8(a0, u3, p3);
      // s=1: issue w(s=2); consume a1 x v*
      u0 = wlA[2 * NTHREADS]; u1 = wlA[6 * NTHREADS];
      u2 = wlB[2 * NTHREADS]; u3 = wlB[6 * NTHREADS];
      p0 = dot8(a1, v0, p0); p1 = dot8(a1, v1, p1);
      p2 = dot8(a1, v2, p2); p3 = dot8(a1, v3, p3);
      // s=2: issue w(s=3); consume a2 x u*
      v0 = wlA[3 * NTHREADS]; v1 = wlA[7 * NTHREADS];
      v2 = wlB[3 * NTHREADS]; v3 = wlB[7 * NTHREADS];
      p0 = dot8(a2, u0, p0); p1 = dot8(a2, u1, p1);
      p2 = dot8(a2, u2, p2); p3 = dot8(a2, u3, p3);
      // s=3: issue hv group B (j=4..7); consume a3 x v*
      h8 b0 = hb8[4], b1 = hb8[5], b2 = hb8[6], b3 = hb8[7];
      p0 = dot8(a3, v0, p0); p1 = dot8(a3, v1, p1);
      p2 = dot8(a3, v2, p2); p3 = dot8(a3, v3, p3);
      // jj=0..3: issue hv j=8..11; consume b* x wreg[0..3]
      a0 = hb8[8];
      p0 = dot8(b0, wreg[0], p0);  p1 = dot8(b0, wreg[12], p1);
      p2 = dot8(b0, wreg[24], p2); p3 = dot8(b0, wreg[36], p3);
      a1 = hb8[9];
      p0 = dot8(b1, wreg[1], p0);  p1 = dot8(b1, wreg[13], p1);
      p2 = dot8(b1, wreg[25], p2); p3 = dot8(b1, wreg[37], p3);
      a2 = hb8[10];
      p0 = dot8(b2, wreg[2], p0);  p1 = dot8(b2, wreg[14], p1);
      p2 = dot8(b2, wreg[26], p2); p3 = dot8(b2, wreg[38], p3);
      a3 = hb8[11];
      p0 = dot8(b3, wreg[3], p0);  p1 = dot8(b3, wreg[15], p1);
      p2 = dot8(b3, wreg[27], p2); p3 = dot8(b3, wreg[39], p3);
      // jj=4..7: issue hv j=12..15; consume a* x wreg[4..7]
      b0 = hb8[12];
      p0 = dot8(a0, wreg[4], p0);  p1 = dot8(a0, wreg[16], p1);
      p2 = dot8(a0, wreg[28], p2); p3 = dot8(a0, wreg[40], p3);
      b1 = hb8[13];
      p0 = dot8(a1, wreg[5], p0);  p1 = dot8(a1, wreg[17], p1);
      p2 = dot8(a1, wreg[29], p2); p3 = dot8(a1, wreg[41], p3);
      b2 = hb8[14];
      p0 = dot8(a2, wreg[6], p0);  p1 = dot8(a2, wreg[18], p1);
      p2 = dot8(a2, wreg[30], p2); p3 = dot8(a2, wreg[42], p3);
      b3 = hb8[15];
      p0 = dot8(a3, wreg[7], p0);  p1 = dot8(a3, wreg[19], p1);
      p2 = dot8(a3, wreg[31], p2); p3 = dot8(a3, wreg[43], p3);
      // jj=8..11: consume b* x wreg[8..11]
      p0 = dot8(b0, wreg[8], p0);  p1 = dot8(b0, wreg[20], p1);
      p2 = dot8(b0, wreg[32], p2); p3 = dot8(b0, wreg[44], p3);
      p0 = dot8(b1, wreg[9], p0);  p1 = dot8(b1, wreg[21], p1);
      p2 = dot8(b1, wreg[33], p2); p3 = dot8(b1, wreg[45], p3);
      p0 = dot8(b2, wreg[10], p0); p1 = dot8(b2, wreg[22], p1);
      p2 = dot8(b2, wreg[34], p2); p3 = dot8(b2, wreg[46], p3);
      p0 = dot8(b3, wreg[11], p0); p1 = dot8(b3, wreg[23], p1);
      p2 = dot8(b3, wreg[35], p2); p3 = dot8(b3, wreg[47], p3);
      // xor-1 DPP butterfly: both lanes of the pair get all 4 full sums.
      p0 += qperm<0xB1>(p0);
      p1 += qperm<0xB1>(p1);
      p2 += qperm<0xB1>(p2);
      p3 += qperm<0xB1>(p3);
      float gi = sigmoidf_(p0 + (float)xg4[0]);
      float gf = sigmoidf_(p1 + (float)xg4[1]);
      float gg = tanhfast(p2 + (float)xg4[2]);
      float go = sigmoidf_(p3 + (float)xg4[3]);
      c_state = gf * c_state + gi * gg;
      float hval = go * tanhfast(c_state);
      if (jhalf == 0) {  // one lane per unit publishes
        _Float16 hh = (_Float16)hval;
        ((_Float16*)&hbuf[(t + 1) & 1][(q >> 7) * HHALF])[q & 127] = hh;
        ((_Float16*)hch)[t * NH + q] = hh;  // history for layer2
      }
      __syncthreads();  // h(t+1) visible; hbuf[t&1] free for step t+2's write
    }

    // ---- layer2: x2 = relu(h @ W2^T + b2); W2 row double-buffered ----
    {
      const int o = tid & 255;
      const int tb = (tid >> 8) * 4;  // 4 timesteps per thread
      float acc[4] = {b2v, b2v, b2v, b2v};
      const h8* wrow = (const h8*)w2w + o * 32;
      const h8* hs = (const h8*)hch + tb * 32;  // xv = hs[tt*32 + c*4 + qq]
      h8 wa[4], wb[4];
#pragma unroll
      for (int qq = 0; qq < 4; qq++) wa[qq] = wrow[qq];
#pragma unroll
      for (int cc = 0; cc < 4; cc++) {
        const int ce = 2 * cc, codd = 2 * cc + 1;
        const int cn = (2 * cc + 2 < 8) ? 2 * cc + 2 : 7;  // tail reread, harmless
#pragma unroll
        for (int qq = 0; qq < 4; qq++) wb[qq] = wrow[codd * 4 + qq];
#pragma unroll
        for (int tt = 0; tt < 4; tt++)
#pragma unroll
          for (int qq = 0; qq < 4; qq++)
            acc[tt] = dot8(hs[tt * 32 + ce * 4 + qq], wa[qq], acc[tt]);
#pragma unroll
        for (int qq = 0; qq < 4; qq++) wa[qq] = wrow[cn * 4 + qq];
#pragma unroll
        for (int tt = 0; tt < 4; tt++)
#pragma unroll
          for (int qq = 0; qq < 4; qq++)
            acc[tt] = dot8(hs[tt * 32 + codd * 4 + qq], wb[qq], acc[tt]);
      }
#pragma unroll
      for (int tt = 0; tt < 4; tt++)
        ((_Float16*)x2b)[(tb + tt) * NH + o] = (_Float16)fmaxf(acc[tt], 0.f);
    }
    __syncthreads();

    // ---- heads: 32 outputs x 8 timesteps on first 256 threads (verbatim) ----
    if (tid < 256) {
      const int tt = tid >> 5;
      const h8* wrow = (const h8*)wmh + oh * 32;
      float acc = 0.f;
#pragma unroll 4
      for (int c = 0; c < 32; c++) {
        h8 xv = *(const h8*)&x2b[tt * 128 + c * 4];
        acc = dot8(xv, wrow[c], acc);
      }
      acc += hbv;
      const size_t idx = ((size_t)b * NT + (t0 + tt)) * NA + (oh & 15);
      if (oh < NA) {
        out_means[idx] = acc;
      } else {
        float ls = fminf(fmaxf(acc, -20.f), 2.f);
        out_stds[idx] = fexp2(1.4426950408889634f * ls);
      }
    }
    // no trailing barrier: next chunk's first write to x2b (its layer2) is
    // separated from these reads by the staging/xg/step barriers.
  }
}

extern "C" void kernel_launch(void* const* d_in, const int* in_sizes, int n_in,
                              void* d_out, int out_size, void* d_ws, size_t ws_size,
                              hipStream_t stream) {
  const float* obs = (const float*)d_in[0];
  const float* Wih = (const float*)d_in[1];
  const float* Whh = (const float*)d_in[2];
  const float* bih = (const float*)d_in[3];
  const float* bhh = (const float*)d_in[4];
  const float* W2 = (const float*)d_in[5];
  const float* b2 = (const float*)d_in[6];
  const float* Wm = (const float*)d_in[7];
  const float* bm = (const float*)d_in[8];
  const float* Ws = (const float*)d_in[9];
  const float* bs = (const float*)d_in[10];

  char* ws = (char*)d_ws;
  h2* whh = (h2*)(ws + 0);            // 512 KB
  h2* wih = (h2*)(ws + 524288);       // 128 KB
  h2* w2w = (h2*)(ws + 655360);       // 128 KB
  h2* wmh = (h2*)(ws + 786432);       // 16 KB
  float* bg = (float*)(ws + 802816);  // 4 KB

  prep_kernel<<<512, 256, 0, stream>>>(Wih, Whh, bih, bhh, W2, Wm, Ws,
                                       whh, wih, w2w, wmh, bg);
  actor_kernel<<<NB, NTHREADS, 0, stream>>>(obs, whh, wih, w2w, wmh, bg, b2, bm,
                                            bs, (float*)d_out);
}

// Round 14
// 3822.840 us; speedup vs baseline: 1.9843x; 1.1268x over previous
//
#include <hip/hip_runtime.h>

// RecurrentGaussianActor: fused LSTM(64->256) + Linear+ReLU(256) + 2 heads(16).
// One WG per batch row (256 WGs x 512 threads), persistent over T=1000 steps.
//
// Round-14: configuration of record (r8/r13, 4300us) with ONE change: every
// in-loop __syncthreads() -> raw { s_waitcnt lgkmcnt(0); s_barrier }.
// Mechanism: __syncthreads compiles to s_waitcnt vmcnt(0) expcnt(0)
// lgkmcnt(0) + s_barrier; the vmcnt(0) drain forces every wave to wait for
// ALL outstanding VMEM at each of the 10 barriers/chunk -- including the ~3
// h8/thread/step scratch spill reloads (~900cy HBM) that r10-r12 proved are
// otherwise well-scheduled. Correctness needs only lgkmcnt(0): all
// cross-thread data (hbuf/hch/x2b/xbuf/gbuf-free design) moves through LDS;
// global stores go to out (never read back); scratch is thread-private; the
// obs staging load's v->ds_write dependency gets its own compiler waitcnt.
// Everything else is r13 bit-identical.
// Tells: dur < 4200 = drain was real; ~4300 neutral = barrier drain is not
// the stall and 4300 is the structural minimum for this decomposition.

#define NB 256
#define NT 1000
#define NF 64
#define NH 256
#define NG 1024
#define NA 16
#define NTHREADS 512
#define CHUNK 8
#define NCHUNK (NT / CHUNK)
#define HHALF 68  // h2 units per padded h-half: 128 f16 = 64 h2, +4 h2 pad = 272 B

// Raw barrier: DS ordering only (no vmcnt drain). "memory" clobber keeps
// LDS ops from migrating across; the builtin emits a bare s_barrier.
#define BARRIER()                                          \
  do {                                                     \
    asm volatile("s_waitcnt lgkmcnt(0)" ::: "memory");     \
    __builtin_amdgcn_s_barrier();                          \
  } while (0)

typedef _Float16 h2 __attribute__((ext_vector_type(2)));
typedef _Float16 h4 __attribute__((ext_vector_type(4)));
typedef _Float16 h8 __attribute__((ext_vector_type(8)));
typedef float f4 __attribute__((ext_vector_type(4)));

__device__ __forceinline__ float fdot2(h2 a, h2 b, float c) {
  return __builtin_amdgcn_fdot2(a, b, c, false);
}
__device__ __forceinline__ float fexp2(float x) { return __builtin_amdgcn_exp2f(x); }
__device__ __forceinline__ float frcp(float x) { return __builtin_amdgcn_rcpf(x); }
__device__ __forceinline__ float sigmoidf_(float x) {
  return frcp(1.f + fexp2(-1.4426950408889634f * x));
}
__device__ __forceinline__ float tanhfast(float x) {
  float a = fabsf(x);
  float e = fexp2(-2.8853900817779268f * a);
  float r = (1.f - e) * frcp(1.f + e);
  return __builtin_copysignf(r, x);
}
// dot of 8 f16 elements held in two h8 vectors (4 chained v_dot2_f32_f16)
__device__ __forceinline__ float dot8(h8 x, h8 w, float acc) {
  acc = fdot2(__builtin_shufflevector(x, x, 0, 1), __builtin_shufflevector(w, w, 0, 1), acc);
  acc = fdot2(__builtin_shufflevector(x, x, 2, 3), __builtin_shufflevector(w, w, 2, 3), acc);
  acc = fdot2(__builtin_shufflevector(x, x, 4, 5), __builtin_shufflevector(w, w, 4, 5), acc);
  acc = fdot2(__builtin_shufflevector(x, x, 6, 7), __builtin_shufflevector(w, w, 6, 7), acc);
  return acc;
}
// quad_perm DPP: CTRL=0xB1 -> lanes (1,0,3,2) [xor1 within each quad]
template <int CTRL>
__device__ __forceinline__ float qperm(float x) {
  return __int_as_float(
      __builtin_amdgcn_update_dpp(0, __float_as_int(x), CTRL, 0xF, 0xF, true));
}

// ---- prep: convert/pack weights to f16 pairs in workspace (round-0 verbatim) ----
__global__ void prep_kernel(const float* __restrict__ Wih, const float* __restrict__ Whh,
                            const float* __restrict__ bih, const float* __restrict__ bhh,
                            const float* __restrict__ W2, const float* __restrict__ Wm,
                            const float* __restrict__ Ws,
                            h2* __restrict__ whh, h2* __restrict__ wih,
                            h2* __restrict__ w2w, h2* __restrict__ wmh,
                            float* __restrict__ bg) {
  int i = blockIdx.x * 256 + threadIdx.x;
  if (i < 1024 * 128) {  // W_hh [1024][256] -> [1024][128] pairs
    int j = i >> 7, p = i & 127;
    whh[i] = h2{(_Float16)Whh[j * 256 + 2 * p], (_Float16)Whh[j * 256 + 2 * p + 1]};
  }
  if (i < 1024 * 32) {   // W_ih [1024][64] -> [1024][32] pairs
    int j = i >> 5, p = i & 31;
    wih[i] = h2{(_Float16)Wih[j * 64 + 2 * p], (_Float16)Wih[j * 64 + 2 * p + 1]};
  }
  if (i < 256 * 128) {   // W2 [256][256] -> [256][128] pairs
    int j = i >> 7, p = i & 127;
    w2w[i] = h2{(_Float16)W2[j * 256 + 2 * p], (_Float16)W2[j * 256 + 2 * p + 1]};
  }
  if (i < 32 * 128) {    // Wm rows 0..15, Ws rows 16..31
    int j = i >> 7, p = i & 127;
    float v0, v1;
    if (j < 16) { v0 = Wm[j * 256 + 2 * p]; v1 = Wm[j * 256 + 2 * p + 1]; }
    else        { v0 = Ws[(j - 16) * 256 + 2 * p]; v1 = Ws[(j - 16) * 256 + 2 * p + 1]; }
    wmh[i] = h2{(_Float16)v0, (_Float16)v1};
  }
  if (i < 1024) bg[i] = bih[i] + bhh[i];
}

// ---- main fused persistent kernel: 1 WG per batch row ----
__global__ __launch_bounds__(NTHREADS, 2) void actor_kernel(
    const float* __restrict__ obs,
    const h2* __restrict__ whh, const h2* __restrict__ wih,
    const h2* __restrict__ w2w, const h2* __restrict__ wmh,
    const float* __restrict__ bg, const float* __restrict__ b2,
    const float* __restrict__ bm, const float* __restrict__ bs,
    float* __restrict__ out) {
  // W_hh h8-slices 0..3 of this thread's (4 rows x own h-half): 16 columns
  // of [512] h8; reads lane-linear b128 -> conflict-free (r4 layout).
  __shared__ __align__(16) h8 whh_l[16 * NTHREADS];        // 131072 B
  __shared__ __align__(16) _Float16 xg_l[CHUNK * NG];      // 16384 B [t][u][4g]
  __shared__ __align__(16) h2 hbuf[2][2 * HHALF];          // 1088 B padded dbuf h
  __shared__ __align__(16) h2 hch[CHUNK * NH / 2];         // 4096 B  h history
  __shared__ __align__(16) h2 xbuf[CHUNK * NF / 2];        // 1024 B  obs chunk
  __shared__ __align__(16) h2 x2b[CHUNK * NH / 2];         // 4096 B  layer2 out
  // total 157760 B <= 163840

  const int tid = threadIdx.x;
  const int b = blockIdx.x;
  const int q = tid >> 1;      // hidden unit owned by this lane pair
  const int jhalf = tid & 1;   // h-half [128*jhalf, 128*jhalf+128)

  // ---- register-resident W_hh: h8s 4..15 of own half, 4 gate rows of q ----
  // 48 x h8 = 192 regs (the allocator's stable AGPR footprint). VOLATILE:
  // no remat-from-global inside the step loop.
  h8 wreg[48];
  {
    const volatile h8* vw = (const volatile h8*)whh;  // row stride = 32 h8
#pragma unroll
    for (int g = 0; g < 4; g++)
#pragma unroll
      for (int jj = 0; jj < 12; jj++)
        wreg[g * 12 + jj] = vw[(g * 256 + q) * 32 + jhalf * 16 + 4 + jj];
  }
  // ---- LDS-resident W_hh: h8s 0..3 of own half, column (g*4+s), idx tid ----
  {
    const h8* whh8 = (const h8*)whh;
#pragma unroll
    for (int g = 0; g < 4; g++)
#pragma unroll
      for (int s = 0; s < 4; s++)
        whh_l[(g * 4 + s) * NTHREADS + tid] = whh8[(g * 256 + q) * 32 + jhalf * 16 + s];
  }
  if (tid < 2 * HHALF) hbuf[0][tid] = h2{(_Float16)0.f, (_Float16)0.f};
  float c_state = 0.f;  // replicated across the lane pair
  const float bg0 = bg[tid], bg1 = bg[tid + 512];  // xg bias rows tid, tid+512
  const float b2v = b2[tid & 255];
  const int oh = tid & 31;
  const float hbv = (oh < NA) ? bm[oh] : bs[oh - NA];
  __syncthreads();  // init barrier: full drain is fine (runs once)

  const float* obs_b = obs + (size_t)b * NT * NF;
  float* out_means = out;
  float* out_stds = out + (size_t)NB * NT * NA;
  // weight base pointers: all 16 step-loop w-reads become ds_read with
  // compile-time offset: immediates (byte offsets <= 57344 < 64K).
  const h8* wlA = whh_l + tid;                 // gates 0,1: elem (g*4+s)*512
  const h8* wlB = whh_l + 8 * NTHREADS + tid;  // gates 2,3

  for (int ch = 0; ch < NCHUNK; ++ch) {
    const int t0 = ch * CHUNK;

    // ---- stage obs chunk -> f16 pairs in LDS (round-0 verbatim) ----
    if (tid < 128) {
      int t = tid >> 4, fq = tid & 15;
      f4 v = *(const f4*)(obs_b + (size_t)(t0 + t) * NF + fq * 4);
      xbuf[t * 32 + fq * 2] = h2{(_Float16)v[0], (_Float16)v[1]};
      xbuf[t * 32 + fq * 2 + 1] = h2{(_Float16)v[2], (_Float16)v[3]};
    }
    BARRIER();

    // ---- xg for rows tid and tid+512 (round-0 math, [t][u][4g] store) ----
#pragma unroll
    for (int rr = 0; rr < 2; ++rr) {
      const int row = tid + rr * 512;
      const float bias = rr ? bg1 : bg0;
      float acc[CHUNK];
#pragma unroll
      for (int t = 0; t < CHUNK; t++) acc[t] = bias;
      const h8* wrow = (const h8*)wih + row * 8;
#pragma unroll
      for (int jh = 0; jh < 2; jh++) {
        h8 w[4];
#pragma unroll
        for (int qq = 0; qq < 4; qq++) w[qq] = wrow[jh * 4 + qq];
#pragma unroll
        for (int t = 0; t < CHUNK; t++) {
#pragma unroll
          for (int qq = 0; qq < 4; qq++) {
            h8 xv = *(const h8*)&xbuf[t * 32 + jh * 16 + qq * 4];
            acc[t] = dot8(xv, w[qq], acc[t]);
          }
        }
      }
      const int g = row >> 8, uu = row & 255;
#pragma unroll
      for (int t = 0; t < CHUNK; t++)
        xg_l[(t * 256 + uu) * 4 + g] = (_Float16)acc[t];
    }
    BARRIER();

    // ---- 8 recurrent LSTM steps, ONE barrier each; software-pipelined ----
    // Every ds_read is issued >= one dot-group (~128 issue cyc) before its
    // first consumer: hv rotates through a0-3/b0-3, LDS weights through
    // u0-3/v0-3. Same operands/order-of-accumulation as r4.
    for (int t = 0; t < CHUNK; t++) {
      const h8* hb8 =
          (const h8*)((const _Float16*)&hbuf[t & 1][jhalf * HHALF]);
      // issue: hv group A (j=0..3) + w(s=0)
      h8 a0 = hb8[0], a1 = hb8[1], a2 = hb8[2], a3 = hb8[3];
      h8 u0 = wlA[0 * NTHREADS], u1 = wlA[4 * NTHREADS];
      h8 u2 = wlB[0 * NTHREADS], u3 = wlB[4 * NTHREADS];
      h4 xg4 = *(const h4*)&xg_l[(t * 256 + q) * 4];
      float p0 = 0.f, p1 = 0.f, p2 = 0.f, p3 = 0.f;
      // s=0: issue w(s=1); consume a0 x u*
      h8 v0 = wlA[1 * NTHREADS], v1 = wlA[5 * NTHREADS];
      h8 v2 = wlB[1 * NTHREADS], v3 = wlB[5 * NTHREADS];
      p0 = dot8(a0, u0, p0); p1 = dot8(a0, u1, p1);
      p2 = dot8(a0, u2, p2); p3 = dot8(a0, u3, p3);
      // s=1: issue w(s=2); consume a1 x v*
      u0 = wlA[2 * NTHREADS]; u1 = wlA[6 * NTHREADS];
      u2 = wlB[2 * NTHREADS]; u3 = wlB[6 * NTHREADS];
      p0 = dot8(a1, v0, p0); p1 = dot8(a1, v1, p1);
      p2 = dot8(a1, v2, p2); p3 = dot8(a1, v3, p3);
      // s=2: issue w(s=3); consume a2 x u*
      v0 = wlA[3 * NTHREADS]; v1 = wlA[7 * NTHREADS];
      v2 = wlB[3 * NTHREADS]; v3 = wlB[7 * NTHREADS];
      p0 = dot8(a2, u0, p0); p1 = dot8(a2, u1, p1);
      p2 = dot8(a2, u2, p2); p3 = dot8(a2, u3, p3);
      // s=3: issue hv group B (j=4..7); consume a3 x v*
      h8 b0 = hb8[4], b1 = hb8[5], b2 = hb8[6], b3 = hb8[7];
      p0 = dot8(a3, v0, p0); p1 = dot8(a3, v1, p1);
      p2 = dot8(a3, v2, p2); p3 = dot8(a3, v3, p3);
      // jj=0..3: issue hv j=8..11; consume b* x wreg[0..3]
      a0 = hb8[8];
      p0 = dot8(b0, wreg[0], p0);  p1 = dot8(b0, wreg[12], p1);
      p2 = dot8(b0, wreg[24], p2); p3 = dot8(b0, wreg[36], p3);
      a1 = hb8[9];
      p0 = dot8(b1, wreg[1], p0);  p1 = dot8(b1, wreg[13], p1);
      p2 = dot8(b1, wreg[25], p2); p3 = dot8(b1, wreg[37], p3);
      a2 = hb8[10];
      p0 = dot8(b2, wreg[2], p0);  p1 = dot8(b2, wreg[14], p1);
      p2 = dot8(b2, wreg[26], p2); p3 = dot8(b2, wreg[38], p3);
      a3 = hb8[11];
      p0 = dot8(b3, wreg[3], p0);  p1 = dot8(b3, wreg[15], p1);
      p2 = dot8(b3, wreg[27], p2); p3 = dot8(b3, wreg[39], p3);
      // jj=4..7: issue hv j=12..15; consume a* x wreg[4..7]
      b0 = hb8[12];
      p0 = dot8(a0, wreg[4], p0);  p1 = dot8(a0, wreg[16], p1);
      p2 = dot8(a0, wreg[28], p2); p3 = dot8(a0, wreg[40], p3);
      b1 = hb8[13];
      p0 = dot8(a1, wreg[5], p0);  p1 = dot8(a1, wreg[17], p1);
      p2 = dot8(a1, wreg[29], p2); p3 = dot8(a1, wreg[41], p3);
      b2 = hb8[14];
      p0 = dot8(a2, wreg[6], p0);  p1 = dot8(a2, wreg[18], p1);
      p2 = dot8(a2, wreg[30], p2); p3 = dot8(a2, wreg[42], p3);
      b3 = hb8[15];
      p0 = dot8(a3, wreg[7], p0);  p1 = dot8(a3, wreg[19], p1);
      p2 = dot8(a3, wreg[31], p2); p3 = dot8(a3, wreg[43], p3);
      // jj=8..11: consume b* x wreg[8..11]
      p0 = dot8(b0, wreg[8], p0);  p1 = dot8(b0, wreg[20], p1);
      p2 = dot8(b0, wreg[32], p2); p3 = dot8(b0, wreg[44], p3);
      p0 = dot8(b1, wreg[9], p0);  p1 = dot8(b1, wreg[21], p1);
      p2 = dot8(b1, wreg[33], p2); p3 = dot8(b1, wreg[45], p3);
      p0 = dot8(b2, wreg[10], p0); p1 = dot8(b2, wreg[22], p1);
      p2 = dot8(b2, wreg[34], p2); p3 = dot8(b2, wreg[46], p3);
      p0 = dot8(b3, wreg[11], p0); p1 = dot8(b3, wreg[23], p1);
      p2 = dot8(b3, wreg[35], p2); p3 = dot8(b3, wreg[47], p3);
      // xor-1 DPP butterfly: both lanes of the pair get all 4 full sums.
      p0 += qperm<0xB1>(p0);
      p1 += qperm<0xB1>(p1);
      p2 += qperm<0xB1>(p2);
      p3 += qperm<0xB1>(p3);
      float gi = sigmoidf_(p0 + (float)xg4[0]);
      float gf = sigmoidf_(p1 + (float)xg4[1]);
      float gg = tanhfast(p2 + (float)xg4[2]);
      float go = sigmoidf_(p3 + (float)xg4[3]);
      c_state = gf * c_state + gi * gg;
      float hval = go * tanhfast(c_state);
      if (jhalf == 0) {  // one lane per unit publishes
        _Float16 hh = (_Float16)hval;
        ((_Float16*)&hbuf[(t + 1) & 1][(q >> 7) * HHALF])[q & 127] = hh;
        ((_Float16*)hch)[t * NH + q] = hh;  // history for layer2
      }
      BARRIER();  // h(t+1) visible; NO vmcnt drain (spill reloads stay in flight)
    }

    // ---- layer2: x2 = relu(h @ W2^T + b2); W2 row double-buffered ----
    {
      const int o = tid & 255;
      const int tb = (tid >> 8) * 4;  // 4 timesteps per thread
      float acc[4] = {b2v, b2v, b2v, b2v};
      const h8* wrow = (const h8*)w2w + o * 32;
      const h8* hs = (const h8*)hch + tb * 32;  // xv = hs[tt*32 + c*4 + qq]
      h8 wa[4], wb[4];
#pragma unroll
      for (int qq = 0; qq < 4; qq++) wa[qq] = wrow[qq];
#pragma unroll
      for (int cc = 0; cc < 4; cc++) {
        const int ce = 2 * cc, codd = 2 * cc + 1;
        const int cn = (2 * cc + 2 < 8) ? 2 * cc + 2 : 7;  // tail reread, harmless
#pragma unroll
        for (int qq = 0; qq < 4; qq++) wb[qq] = wrow[codd * 4 + qq];
#pragma unroll
        for (int tt = 0; tt < 4; tt++)
#pragma unroll
          for (int qq = 0; qq < 4; qq++)
            acc[tt] = dot8(hs[tt * 32 + ce * 4 + qq], wa[qq], acc[tt]);
#pragma unroll
        for (int qq = 0; qq < 4; qq++) wa[qq] = wrow[cn * 4 + qq];
#pragma unroll
        for (int tt = 0; tt < 4; tt++)
#pragma unroll
          for (int qq = 0; qq < 4; qq++)
            acc[tt] = dot8(hs[tt * 32 + codd * 4 + qq], wb[qq], acc[tt]);
      }
#pragma unroll
      for (int tt = 0; tt < 4; tt++)
        ((_Float16*)x2b)[(tb + tt) * NH + o] = (_Float16)fmaxf(acc[tt], 0.f);
    }
    BARRIER();

    // ---- heads: 32 outputs x 8 timesteps on first 256 threads (verbatim) ----
    if (tid < 256) {
      const int tt = tid >> 5;
      const h8* wrow = (const h8*)wmh + oh * 32;
      float acc = 0.f;
#pragma unroll 4
      for (int c = 0; c < 32; c++) {
        h8 xv = *(const h8*)&x2b[tt * 128 + c * 4];
        acc = dot8(xv, wrow[c], acc);
      }
      acc += hbv;
      const size_t idx = ((size_t)b * NT + (t0 + tt)) * NA + (oh & 15);
      if (oh < NA) {
        out_means[idx] = acc;
      } else {
        float ls = fminf(fmaxf(acc, -20.f), 2.f);
        out_stds[idx] = fexp2(1.4426950408889634f * ls);
      }
    }
    // no trailing barrier: next chunk's first write to x2b (its layer2) is
    // separated from these reads by the staging/xg/step barriers.
  }
}

extern "C" void kernel_launch(void* const* d_in, const int* in_sizes, int n_in,
                              void* d_out, int out_size, void* d_ws, size_t ws_size,
                              hipStream_t stream) {
  const float* obs = (const float*)d_in[0];
  const float* Wih = (const float*)d_in[1];
  const float* Whh = (const float*)d_in[2];
  const float* bih = (const float*)d_in[3];
  const float* bhh = (const float*)d_in[4];
  const float* W2 = (const float*)d_in[5];
  const float* b2 = (const float*)d_in[6];
  const float* Wm = (const float*)d_in[7];
  const float* bm = (const float*)d_in[8];
  const float* Ws = (const float*)d_in[9];
  const float* bs = (const float*)d_in[10];

  char* ws = (char*)d_ws;
  h2* whh = (h2*)(ws + 0);            // 512 KB
  h2* wih = (h2*)(ws + 524288);       // 128 KB
  h2* w2w = (h2*)(ws + 655360);       // 128 KB
  h2* wmh = (h2*)(ws + 786432);       // 16 KB
  float* bg = (float*)(ws + 802816);  // 4 KB

  prep_kernel<<<512, 256, 0, stream>>>(Wih, Whh, bih, bhh, W2, Wm, Ws,
                                       whh, wih, w2w, wmh, bg);
  actor_kernel<<<NB, NTHREADS, 0, stream>>>(obs, whh, wih, w2w, wmh, bg, b2, bm,
                                            bs, (float*)d_out);
}